// Round 15
// baseline (176.612 us; speedup 1.0000x reference)
//
#include <hip/hip_runtime.h>
#include <hip/hip_bf16.h>

typedef __bf16 bf16x8 __attribute__((ext_vector_type(8)));
typedef __bf16 bf16x4 __attribute__((ext_vector_type(4)));
typedef float f32x4 __attribute__((ext_vector_type(4)));
typedef float f32x16 __attribute__((ext_vector_type(16)));

#define NTOK 16384
#define DIN  256
#define DHID 512
#define DOUT 256
#define NEXP 8
#define MAXB 256   // 8 experts x 32 slots, capacity 160 tokens/slot (ce<=5120)

#define MFMA32(a, b, c) __builtin_amdgcn_mfma_f32_32x32x16_bf16(a, b, c, 0, 0, 0)
// async global->LDS, 16B/lane; LDS dest = wave-uniform base + lane*16 (HW rule)
#define GLD16(gp, lp)                                                       \
  __builtin_amdgcn_global_load_lds(                                         \
      (__attribute__((address_space(1))) void*)(gp),                        \
      (__attribute__((address_space(3))) void*)(lp), 16, 0, 0)

// ---------------------------------------------------------------------------
// Fused prep: b<512 -> gate (+x->bf16); b<1024 -> W1 transpose+cvt;
// else -> W2 re-tile (verbatim R5 — verified)
__global__ __launch_bounds__(256) void prep_kernel(
    const float* __restrict__ x, const float* __restrict__ wg,
    const float* __restrict__ w1, const float* __restrict__ w2,
    int* __restrict__ cnt, int* __restrict__ btok, float* __restrict__ bw,
    __bf16* __restrict__ xbf, __bf16* __restrict__ w1bf,
    __bf16* __restrict__ w2bf) {
  __shared__ int lcnt[NEXP];
  __shared__ int lbase[NEXP];
  const int b = blockIdx.x;
  const int tid = threadIdx.x;

  if (b >= 512) {
    if (b < 1024) {  // W1 [E][256k][512h] -> w1bf [E][512h][256k]
      int e = (b - 512) >> 6;
      int flat = ((b - 512) & 63) * 256 + tid;  // [0, 16384)
      int kg = flat >> 9;
      int n = flat & 511;
      const float* s = w1 + ((size_t)e * 256 + (size_t)kg * 8) * 512 + n;
      bf16x8 t;
#pragma unroll
      for (int j = 0; j < 8; ++j) t[j] = (__bf16)s[(size_t)j * 512];
      *(bf16x8*)(w1bf + (size_t)(e * 512 + n) * 256 + kg * 8) = t;
    } else {
      // W2 [E][512hid][256o] -> tiled [e][hc:8][wo:8][kw:4][lane:64][j:8]
      // value = W2[hid=hc*64+kw*16+(lane>>5)*8+j][out=wo*32+(lane&31)]
      int e = (b - 1024) >> 6;
      int fi = ((b - 1024) & 63) * 256 + tid;  // [0, 16384)
      int lane = fi & 63;
      int kw = (fi >> 6) & 3;
      int wo = (fi >> 8) & 7;
      int hc = (fi >> 11) & 7;
      int hid0 = hc * 64 + kw * 16 + (lane >> 5) * 8;
      int o = wo * 32 + (lane & 31);
      const float* s = w2 + ((size_t)e * 512 + hid0) * 256 + o;
      bf16x8 t;
#pragma unroll
      for (int j = 0; j < 8; ++j) t[j] = (__bf16)s[(size_t)j * 256];
      *(bf16x8*)(w2bf + (size_t)e * 131072 + (size_t)fi * 8) = t;
    }
    return;
  }

  // ---- gate part: 8 lanes/token, 32 tokens/block ----
  if (tid < NEXP) lcnt[tid] = 0;

  const int sub = tid & 7;
  const int tslot = tid >> 3;
  const int token = b * 32 + tslot;
  const f32x4* xr = (const f32x4*)(x + (size_t)token * DIN + sub * 32);
  const float* wr0 = wg + (size_t)sub * 32 * NEXP;

  bf16x8 xb[4];
  f32x4 p0 = {0.f, 0.f, 0.f, 0.f}, p1 = {0.f, 0.f, 0.f, 0.f};
#pragma unroll
  for (int j4 = 0; j4 < 8; ++j4) {
    f32x4 xv = xr[j4];
    const float* wr = wr0 + j4 * 32;
#pragma unroll
    for (int d = 0; d < 4; ++d) {
      float xs_ = xv[d];
      p0 += xs_ * *(const f32x4*)(wr + 8 * d);
      p1 += xs_ * *(const f32x4*)(wr + 8 * d + 4);
      xb[j4 >> 1][(j4 & 1) * 4 + d] = (__bf16)xs_;
    }
  }
  {
    bf16x8* xdst = (bf16x8*)(xbf + (size_t)token * DIN + sub * 32);
#pragma unroll
    for (int i = 0; i < 4; ++i) xdst[i] = xb[i];
  }

  double acc[NEXP];
#pragma unroll
  for (int d = 0; d < 4; ++d) {
    acc[d] = (double)p0[d];
    acc[4 + d] = (double)p1[d];
  }
#pragma unroll
  for (int off = 1; off < 8; off <<= 1)
#pragma unroll
    for (int e = 0; e < NEXP; ++e) acc[e] += __shfl_xor(acc[e], off, 64);

  __syncthreads();  // lcnt zeroing visible

  int i1 = 0, i2 = 0, o1 = 0, o2 = 0;
  float w1s = 0.f, w2s = 0.f;
  if (sub == 0) {
    double bv1 = acc[0];
#pragma unroll
    for (int e = 1; e < NEXP; ++e)
      if (acc[e] > bv1) { bv1 = acc[e]; i1 = e; }
    double bv2 = -1e300;
#pragma unroll
    for (int e = 0; e < NEXP; ++e)
      if (e != i1 && acc[e] > bv2) { bv2 = acc[e]; i2 = e; }
    float dd = expf((float)(bv2 - bv1));
    w1s = 1.0f / (1.0f + dd);
    w2s = dd * w1s;
    o1 = atomicAdd(&lcnt[i1], 1);
    o2 = atomicAdd(&lcnt[i2], 1);
  }
  __syncthreads();
  if (tid < NEXP) lbase[tid] = atomicAdd(&cnt[tid], lcnt[tid]);
  __syncthreads();
  if (sub == 0) {
    int s1 = lbase[i1] + o1, s2 = lbase[i2] + o2;
    btok[i1 * NTOK + s1] = token;           // slot 0
    bw[i1 * NTOK + s1] = w1s;
    btok[i2 * NTOK + s2] = token | 16384;   // slot 1 (bit 14)
    bw[i2 * NTOK + s2] = w2s;
  }
}

// ---------------------------------------------------------------------------
// Expert FFN, round 20: 1T makespan (R14's design), register-neutral.
// R14's spill autopsy: unified-file budget at 2 waves/SIMD = 256 regs;
// R12 = 128 VGPR + 64 AGPR = 192 OK; R14's xB[2][16] (+64) + acc[5] (+16)
// = 272 -> scratch (WRITE 64 MB). Fix: the two extra phase-A tasks (g=4,
// waves 0-1, SAME 32 tokens) read their B-operand from a 16 KB LDS buffer
// xs2 (staged once in prologue, wb1-style XOR swizzle) instead of a second
// register set. Budget: 128 + 80 = 208 <= 256. Grid 256 = 8 experts x 32
// capacity-160 slots = exactly 1 block/CU => makespan 1T (R12's 52.6 was
// 2T on straggler CUs; occupancy 12.5% matched that model exactly).
__global__ __launch_bounds__(512, 2) void ffn_kernel(
    const __bf16* __restrict__ xbf, const __bf16* __restrict__ w1bf,
    const __bf16* __restrict__ w2bf, const float* __restrict__ b1g,
    const float* __restrict__ b2g, const int* __restrict__ cnt,
    const int* __restrict__ btok, const float* __restrict__ bw,
    __bf16* __restrict__ pout) {
  __shared__ __align__(16) __bf16 wb1[2][64 * 256];  // 64 KiB dbuf, slot^(n&31)
  __shared__ __align__(16) __bf16 hs[160 * 64];      // 20 KiB, slot^(m&7)
  __shared__ __align__(16) __bf16 xs2[32 * 256];     // 16 KiB, tokens 128-159
  __shared__ int tok[160];
  __shared__ int srow[160];
  __shared__ float wgt[160];
  __shared__ float b1s[DHID];
  __shared__ float b2s[DOUT];

  // XCD-affine mapping, 32 slots x 160 tokens per expert
  const int e = blockIdx.x & 7;
  const int ce = cnt[e];
  const int start = (blockIdx.x >> 3) * 160;
  if (start >= ce) return;
  const int rot = (blockIdx.x >> 3) & 7;  // chunk-phase decorrelation

  const int tid = threadIdx.x;
  if (tid < 160) {
    int idx = start + tid;
    bool v = idx < ce;
    int entry = v ? btok[e * NTOK + idx] : 0;
    int tk = entry & 16383;
    tok[tid] = tk;
    srow[tid] = (entry >> 14) * NTOK + tk;
    wgt[tid] = v ? bw[e * NTOK + idx] : 0.0f;
  }
  if (tid < 256) b2s[tid] = b2g[e * DOUT + tid];
  b1s[tid & 511] = b1g[e * DHID + (tid & 511)];
  __syncthreads();  // tok[] visible for xs2 staging + xB loads

  const int lane = tid & 63;
  const int wid = tid >> 6;      // 0..7
  const int hi = lane >> 5;
  const int l31 = lane & 31;
  const int wo = wid;            // phase B: out quarter (out32 per wave)

  // ---- stage xs2: tokens 128..159, row r = token, 32 slots of 16B,
  // slot stored at (sk ^ r) — same XOR family as wb1 (proven conflict level)
  {
#pragma unroll
    for (int i = 0; i < 2; ++i) {
      int f = tid * 2 + i;          // 0..1023
      int r = f >> 5;               // 0..31
      int sk = f & 31;              // 16B slot (k = sk*8)
      bf16x8 v = *(const bf16x8*)(xbf + (size_t)tok[128 + r] * DIN + sk * 8);
      *(bf16x8*)((char*)xs2 + r * 512 + (sk ^ r) * 16) = v;
    }
  }

  // x as phase-A B-operand in regs for task t=wid: g = wid>>1, col = g*32+l31
  bf16x8 xB[16];
  {
    int g = wid >> 1;
    const __bf16* xr = xbf + (size_t)tok[g * 32 + l31] * DIN + hi * 8;
#pragma unroll
    for (int kw = 0; kw < 16; ++kw) xB[kw] = *(const bf16x8*)(xr + kw * 16);
  }

  const __bf16* w1e = w1bf + (size_t)e * DHID * DIN;
  const __bf16* w2e = w2bf + (size_t)e * 131072;

  f32x16 acc[5];
#pragma unroll
  for (int bi = 0; bi < 5; ++bi)
#pragma unroll
    for (int r = 0; r < 16; ++r) acc[bi][r] = 0.f;

  // xs2 writes must be visible to waves 0-1 before first phase A
  asm volatile("s_waitcnt lgkmcnt(0)" ::: "memory");
  __syncthreads();

  // W1 stage: 32 windows of 1 KiB; each of 8 waves stages 4.
#define STAGE_W1(bufidx, hcv)                                               \
  {                                                                         \
    _Pragma("unroll")                                                       \
    for (int j = 0; j < 4; ++j) {                                           \
      int W = wid * 4 + j;                                                  \
      int n1 = 2 * W + hi;                                                  \
      int s1 = l31 ^ (n1 & 31);                                             \
      GLD16(w1e + (size_t)((hcv) * 64 + n1) * DIN + s1 * 8,                 \
            &wb1[bufidx][W * 512]);                                         \
    }                                                                       \
  }
  // W2 fragments for chunk hcv -> wfrP[slot]
#define LOAD_W2(slot, hcv)                                                  \
  {                                                                         \
    const __bf16* w2t = w2e + (size_t)(((hcv) * 8 + wo) * 4) * 512;         \
    _Pragma("unroll")                                                       \
    for (int kw = 0; kw < 4; ++kw)                                          \
      wfrP[slot][kw] = *(const bf16x8*)(w2t + kw * 512 + lane * 8);         \
  }

  bf16x8 wfrP[2][4];
  STAGE_W1(0, rot);
  LOAD_W2(0, rot);

#pragma unroll
  for (int hc0 = 0; hc0 < 8; ++hc0) {
    const int hc = (hc0 + rot) & 7;
    const int cur = hc0 & 1;

    if (hc0 < 7) {
      const int hcn = (hc0 + 1 + rot) & 7;
      STAGE_W1(cur ^ 1, hcn);
      LOAD_W2(cur ^ 1, hcn);
      // retire chunk i's staged ops; chunk i+1's 8 newest stay in flight
      asm volatile("s_waitcnt vmcnt(8)" ::: "memory");
    } else {
      asm volatile("s_waitcnt vmcnt(0)" ::: "memory");
    }
    __builtin_amdgcn_sched_barrier(0);
    __builtin_amdgcn_s_barrier();       // wb1[cur] complete; B(i-1) done => hs WAR
    __builtin_amdgcn_sched_barrier(0);

    // ---- phase A task 1 (all waves): t = wid, hh = wid&1, g = wid>>1
    {
      const int hh = wid & 1;
      const int g = wid >> 1;
      f32x16 Sp[2];
#pragma unroll
      for (int r = 0; r < 16; ++r) { Sp[0][r] = 0.f; Sp[1][r] = 0.f; }
#pragma unroll
      for (int kw = 0; kw < 16; ++kw) {
        int row = hh * 32 + l31;
        int s = (kw * 2 + hi) ^ (row & 31);
        bf16x8 a =
            *(const bf16x8*)((const char*)&wb1[cur][0] + row * 512 + s * 16);
        Sp[kw & 1] = MFMA32(a, xB[kw], Sp[kw & 1]);
      }
      f32x16 S = Sp[0] + Sp[1];
#pragma unroll
      for (int q = 0; q < 4; ++q) {
        int hl = hh * 32 + 8 * q + 4 * hi;   // local hid, 4-aligned
        f32x4 bv = *(const f32x4*)(&b1s[hc * 64 + hl]);
        bf16x4 pk;
#pragma unroll
        for (int r = 0; r < 4; ++r)
          pk[r] = (__bf16)fmaxf(S[4 * q + r] + bv[r], 0.f);
        int m = g * 32 + l31;                // token row (0..127)
        int slt = (hl >> 3) ^ (m & 7);
        *(bf16x4*)((char*)hs + m * 128 + slt * 16 + (hl & 7) * 2) = pk;
      }
    }
    // ---- phase A task 2 (waves 0-1): g = 4, hh = wid, B-operand from xs2
    if (wid < 2) {
      const int hh = wid;
      f32x16 Sp[2];
#pragma unroll
      for (int r = 0; r < 16; ++r) { Sp[0][r] = 0.f; Sp[1][r] = 0.f; }
#pragma unroll
      for (int kw = 0; kw < 16; ++kw) {
        int row = hh * 32 + l31;
        int s = (kw * 2 + hi) ^ (row & 31);
        bf16x8 a =
            *(const bf16x8*)((const char*)&wb1[cur][0] + row * 512 + s * 16);
        int sx = (kw * 2 + hi) ^ l31;
        bf16x8 xb2 = *(const bf16x8*)((const char*)xs2 + l31 * 512 + sx * 16);
        Sp[kw & 1] = MFMA32(a, xb2, Sp[kw & 1]);
      }
      f32x16 S = Sp[0] + Sp[1];
#pragma unroll
      for (int q = 0; q < 4; ++q) {
        int hl = hh * 32 + 8 * q + 4 * hi;
        f32x4 bv = *(const f32x4*)(&b1s[hc * 64 + hl]);
        bf16x4 pk;
#pragma unroll
        for (int r = 0; r < 4; ++r)
          pk[r] = (__bf16)fmaxf(S[4 * q + r] + bv[r], 0.f);
        int m = 128 + l31;                   // token row (128..159)
        int slt = (hl >> 3) ^ (m & 7);
        *(bf16x4*)((char*)hs + m * 128 + slt * 16 + (hl & 7) * 2) = pk;
      }
    }
    asm volatile("s_waitcnt lgkmcnt(0)" ::: "memory");  // own ds ops done
    __builtin_amdgcn_sched_barrier(0);
    __builtin_amdgcn_s_barrier();       // hs visible (vmcnt NOT drained)
    __builtin_amdgcn_sched_barrier(0);

    // ---- phase B: acc[out32 x tok160] += W2c^T x h, K=64 (W2 from regs)
#pragma unroll
    for (int kw = 0; kw < 4; ++kw) {
#pragma unroll
      for (int bi = 0; bi < 5; ++bi) {
        int m = bi * 32 + l31;
        int s = (kw * 2 + hi) ^ (m & 7);
        bf16x8 hf = *(const bf16x8*)((const char*)hs + m * 128 + s * 16);
        acc[bi] = MFMA32(wfrP[cur][kw], hf, acc[bi]);
      }
    }
  }
#undef STAGE_W1
#undef LOAD_W2

  // ---- epilogue: pout[srow[t]][oc] = bf16(w * (acc + b2)); 8B stores
#pragma unroll
  for (int bi = 0; bi < 5; ++bi) {
    int tm = bi * 32 + l31;
    if (start + tm < ce) {
      float wv = wgt[tm];
      __bf16* prow = pout + (size_t)srow[tm] * DOUT;
#pragma unroll
      for (int q = 0; q < 4; ++q) {
        int o0 = wo * 32 + 8 * q + 4 * hi;
        f32x4 bv = *(const f32x4*)(&b2s[o0]);
        bf16x4 pk;
#pragma unroll
        for (int r = 0; r < 4; ++r)
          pk[r] = (__bf16)(wv * (acc[bi][4 * q + r] + bv[r]));
        *(bf16x4*)(prow + o0) = pk;
      }
    }
  }
}

// ---------------------------------------------------------------------------
// out[t][c] = pout[0][t][c] + pout[1][t][c]   (streaming, 8 elems/thread)
__global__ __launch_bounds__(256) void combine_kernel(const __bf16* __restrict__ pout,
                                                      float* __restrict__ out) {
  int f = blockIdx.x * 256 + threadIdx.x;  // [0, NTOK*DOUT/8)
  bf16x8 a = *(const bf16x8*)(pout + (size_t)f * 8);
  bf16x8 b = *(const bf16x8*)(pout + (size_t)NTOK * DOUT + (size_t)f * 8);
  float4 o0, o1;
  o0.x = (float)a[0] + (float)b[0];
  o0.y = (float)a[1] + (float)b[1];
  o0.z = (float)a[2] + (float)b[2];
  o0.w = (float)a[3] + (float)b[3];
  o1.x = (float)a[4] + (float)b[4];
  o1.y = (float)a[5] + (float)b[5];
  o1.z = (float)a[6] + (float)b[6];
  o1.w = (float)a[7] + (float)b[7];
  float4* dst = (float4*)(out + (size_t)f * 8);
  dst[0] = o0;
  dst[1] = o1;
}

// ---------------------------------------------------------------------------
extern "C" void kernel_launch(void* const* d_in, const int* in_sizes, int n_in,
                              void* d_out, int out_size, void* d_ws, size_t ws_size,
                              hipStream_t stream) {
  const float* x = (const float*)d_in[0];
  const float* Wg = (const float*)d_in[1];
  const float* W1 = (const float*)d_in[2];
  const float* b1 = (const float*)d_in[3];
  const float* W2 = (const float*)d_in[4];
  const float* b2 = (const float*)d_in[5];
  float* out = (float*)d_out;

  char* ws = (char*)d_ws;
  int* cnt = (int*)(ws + 0);                    //      32 B
  int* btok = (int*)(ws + 256);                 //  512 KiB
  float* bw = (float*)(ws + 524544);            //  512 KiB
  __bf16* xbf = (__bf16*)(ws + 1048832);        //    8 MiB
  __bf16* w1bf = (__bf16*)(ws + 9437440);       //    2 MiB
  __bf16* w2bf = (__bf16*)(ws + 11534592);      //    2 MiB
  __bf16* pout = (__bf16*)(ws + 13631744);      //   16 MiB (end ~29 MiB)

  hipMemsetAsync(cnt, 0, NEXP * sizeof(int), stream);

  prep_kernel<<<dim3(1536), dim3(256), 0, stream>>>(x, Wg, W1, W2, cnt, btok,
                                                    bw, xbf, w1bf, w2bf);
  ffn_kernel<<<dim3(MAXB), dim3(512), 0, stream>>>(xbf, w1bf, w2bf, b1, b2,
                                                   cnt, btok, bw, pout);
  combine_kernel<<<dim3(NTOK * DOUT / 8 / 256), dim3(256), 0, stream>>>(pout, out);
}

// Round 16
// 155.881 us; speedup vs baseline: 1.1330x; 1.1330x over previous
//
#include <hip/hip_runtime.h>
#include <hip/hip_bf16.h>

typedef __bf16 bf16x8 __attribute__((ext_vector_type(8)));
typedef __bf16 bf16x4 __attribute__((ext_vector_type(4)));
typedef float f32x4 __attribute__((ext_vector_type(4)));
typedef float f32x16 __attribute__((ext_vector_type(16)));

#define NTOK 16384
#define DIN  256
#define DHID 512
#define DOUT 256
#define NEXP 8
#define MAXB 1024  // 8 experts x 128 slots (covers worst-case cnt_e = 16384)

#define MFMA32(a, b, c) __builtin_amdgcn_mfma_f32_32x32x16_bf16(a, b, c, 0, 0, 0)
// async global->LDS, 16B/lane; LDS dest = wave-uniform base + lane*16 (HW rule)
#define GLD16(gp, lp)                                                       \
  __builtin_amdgcn_global_load_lds(                                         \
      (__attribute__((address_space(1))) void*)(gp),                        \
      (__attribute__((address_space(3))) void*)(lp), 16, 0, 0)

// ---------------------------------------------------------------------------
// Fused prep: b<512 -> gate (+x->bf16); b<1024 -> W1 transpose+cvt;
// else -> W2 re-tile (verbatim R5 — verified)
__global__ __launch_bounds__(256) void prep_kernel(
    const float* __restrict__ x, const float* __restrict__ wg,
    const float* __restrict__ w1, const float* __restrict__ w2,
    int* __restrict__ cnt, int* __restrict__ btok, float* __restrict__ bw,
    __bf16* __restrict__ xbf, __bf16* __restrict__ w1bf,
    __bf16* __restrict__ w2bf) {
  __shared__ int lcnt[NEXP];
  __shared__ int lbase[NEXP];
  const int b = blockIdx.x;
  const int tid = threadIdx.x;

  if (b >= 512) {
    if (b < 1024) {  // W1 [E][256k][512h] -> w1bf [E][512h][256k]
      int e = (b - 512) >> 6;
      int flat = ((b - 512) & 63) * 256 + tid;  // [0, 16384)
      int kg = flat >> 9;
      int n = flat & 511;
      const float* s = w1 + ((size_t)e * 256 + (size_t)kg * 8) * 512 + n;
      bf16x8 t;
#pragma unroll
      for (int j = 0; j < 8; ++j) t[j] = (__bf16)s[(size_t)j * 512];
      *(bf16x8*)(w1bf + (size_t)(e * 512 + n) * 256 + kg * 8) = t;
    } else {
      // W2 [E][512hid][256o] -> tiled [e][hc:8][wo:8][kw:4][lane:64][j:8]
      // value = W2[hid=hc*64+kw*16+(lane>>5)*8+j][out=wo*32+(lane&31)]
      int e = (b - 1024) >> 6;
      int fi = ((b - 1024) & 63) * 256 + tid;  // [0, 16384)
      int lane = fi & 63;
      int kw = (fi >> 6) & 3;
      int wo = (fi >> 8) & 7;
      int hc = (fi >> 11) & 7;
      int hid0 = hc * 64 + kw * 16 + (lane >> 5) * 8;
      int o = wo * 32 + (lane & 31);
      const float* s = w2 + ((size_t)e * 512 + hid0) * 256 + o;
      bf16x8 t;
#pragma unroll
      for (int j = 0; j < 8; ++j) t[j] = (__bf16)s[(size_t)j * 256];
      *(bf16x8*)(w2bf + (size_t)e * 131072 + (size_t)fi * 8) = t;
    }
    return;
  }

  // ---- gate part: 8 lanes/token, 32 tokens/block ----
  if (tid < NEXP) lcnt[tid] = 0;

  const int sub = tid & 7;
  const int tslot = tid >> 3;
  const int token = b * 32 + tslot;
  const f32x4* xr = (const f32x4*)(x + (size_t)token * DIN + sub * 32);
  const float* wr0 = wg + (size_t)sub * 32 * NEXP;

  bf16x8 xb[4];
  f32x4 p0 = {0.f, 0.f, 0.f, 0.f}, p1 = {0.f, 0.f, 0.f, 0.f};
#pragma unroll
  for (int j4 = 0; j4 < 8; ++j4) {
    f32x4 xv = xr[j4];
    const float* wr = wr0 + j4 * 32;
#pragma unroll
    for (int d = 0; d < 4; ++d) {
      float xs_ = xv[d];
      p0 += xs_ * *(const f32x4*)(wr + 8 * d);
      p1 += xs_ * *(const f32x4*)(wr + 8 * d + 4);
      xb[j4 >> 1][(j4 & 1) * 4 + d] = (__bf16)xs_;
    }
  }
  {
    bf16x8* xdst = (bf16x8*)(xbf + (size_t)token * DIN + sub * 32);
#pragma unroll
    for (int i = 0; i < 4; ++i) xdst[i] = xb[i];
  }

  double acc[NEXP];
#pragma unroll
  for (int d = 0; d < 4; ++d) {
    acc[d] = (double)p0[d];
    acc[4 + d] = (double)p1[d];
  }
#pragma unroll
  for (int off = 1; off < 8; off <<= 1)
#pragma unroll
    for (int e = 0; e < NEXP; ++e) acc[e] += __shfl_xor(acc[e], off, 64);

  __syncthreads();  // lcnt zeroing visible

  int i1 = 0, i2 = 0, o1 = 0, o2 = 0;
  float w1s = 0.f, w2s = 0.f;
  if (sub == 0) {
    double bv1 = acc[0];
#pragma unroll
    for (int e = 1; e < NEXP; ++e)
      if (acc[e] > bv1) { bv1 = acc[e]; i1 = e; }
    double bv2 = -1e300;
#pragma unroll
    for (int e = 0; e < NEXP; ++e)
      if (e != i1 && acc[e] > bv2) { bv2 = acc[e]; i2 = e; }
    float dd = expf((float)(bv2 - bv1));
    w1s = 1.0f / (1.0f + dd);
    w2s = dd * w1s;
    o1 = atomicAdd(&lcnt[i1], 1);
    o2 = atomicAdd(&lcnt[i2], 1);
  }
  __syncthreads();
  if (tid < NEXP) lbase[tid] = atomicAdd(&cnt[tid], lcnt[tid]);
  __syncthreads();
  if (sub == 0) {
    int s1 = lbase[i1] + o1, s2 = lbase[i2] + o2;
    btok[i1 * NTOK + s1] = token;           // slot 0
    bw[i1 * NTOK + s1] = w1s;
    btok[i2 * NTOK + s2] = token | 16384;   // slot 1 (bit 14)
    bw[i2 * NTOK + s2] = w2s;
  }
}

// ---------------------------------------------------------------------------
// Expert FFN (R12, best measured): R5 body verbatim (straight-line, spill-
// free) with XCD-affine mapping: e = blockIdx&7, slot = blockIdx>>3. With
// round-robin blockIdx->XCD dispatch (guide T1), every block of expert e
// lands on XCD e: its 512 KB weight set crosses the fabric once and stays
// hot in the local 4 MB L2 (FETCH 30 -> 10.5 MB measured). Session plateau
// note: ffn = 2 x T128 makespan (258 tiles on 256 CUs); 1T-makespan variants
// (capacity-160 tiles) all exceeded the 256-reg/wave budget and spilled
// (R13/R14/R15); loops around the body spill (R7/R11); single-buffer wb1
// raises per-tile time more than pairing saves (R13).
__global__ __launch_bounds__(512, 2) void ffn_kernel(
    const __bf16* __restrict__ xbf, const __bf16* __restrict__ w1bf,
    const __bf16* __restrict__ w2bf, const float* __restrict__ b1g,
    const float* __restrict__ b2g, const int* __restrict__ cnt,
    const int* __restrict__ btok, const float* __restrict__ bw,
    __bf16* __restrict__ pout) {
  __shared__ __align__(16) __bf16 wb1[2][64 * 256];  // dbuf [hid64][k256], slot^(n&31)
  __shared__ __align__(16) __bf16 hs[128 * 64];      // [tok128][hid64], slot^(m&7)
  __shared__ int tok[128];
  __shared__ int srow[128];
  __shared__ float wgt[128];
  __shared__ float b1s[DHID];
  __shared__ float b2s[DOUT];

  // XCD-affine mapping
  const int e = blockIdx.x & 7;
  const int ce = cnt[e];
  const int start = (blockIdx.x >> 3) * 128;
  if (start >= ce) return;
  const int rot = (blockIdx.x >> 3) & 7;  // chunk-phase decorrelation

  const int tid = threadIdx.x;
  if (tid < 128) {
    int idx = start + tid;
    bool v = idx < ce;
    int entry = v ? btok[e * NTOK + idx] : 0;
    int tk = entry & 16383;
    tok[tid] = tk;
    srow[tid] = (entry >> 14) * NTOK + tk;
    wgt[tid] = v ? bw[e * NTOK + idx] : 0.0f;
  }
  if (tid < 256) b2s[tid] = b2g[e * DOUT + tid];
  b1s[tid & 511] = b1g[e * DHID + (tid & 511)];
  __syncthreads();

  const int lane = tid & 63;
  const int wid = tid >> 6;      // 0..7
  const int hi = lane >> 5;
  const int l31 = lane & 31;
  const int wh = wid >> 2;       // phase A: hid half (0..1)
  const int wtq = wid & 3;       // phase A: token quarter (0..3)

  // x as phase-A B-operand in registers: B[k][tok-col], col = wtq*32+l31.
  bf16x8 xB[16];
  {
    const __bf16* xr = xbf + (size_t)tok[wtq * 32 + l31] * DIN + hi * 8;
#pragma unroll
    for (int kw = 0; kw < 16; ++kw) xB[kw] = *(const bf16x8*)(xr + kw * 16);
  }

  const __bf16* w1e = w1bf + (size_t)e * DHID * DIN;
  const __bf16* w2e = w2bf + (size_t)e * 131072;

  f32x16 acc[4];
#pragma unroll
  for (int bi = 0; bi < 4; ++bi)
#pragma unroll
    for (int r = 0; r < 16; ++r) acc[bi][r] = 0.f;

  // W1 stage: 32 windows of 1 KiB; each of 8 waves stages 4.
#define STAGE_W1(bufidx, hcv)                                               \
  {                                                                         \
    _Pragma("unroll")                                                       \
    for (int j = 0; j < 4; ++j) {                                           \
      int W = wid * 4 + j;                                                  \
      int n1 = 2 * W + hi;                                                  \
      int s1 = l31 ^ (n1 & 31);                                             \
      GLD16(w1e + (size_t)((hcv) * 64 + n1) * DIN + s1 * 8,                 \
            &wb1[bufidx][W * 512]);                                         \
    }                                                                       \
  }
  // W2 fragments for chunk hcv -> wfrP[slot]
#define LOAD_W2(slot, hcv)                                                  \
  {                                                                         \
    const __bf16* w2t = w2e + (size_t)(((hcv) * 8 + wid) * 4) * 512;        \
    _Pragma("unroll")                                                       \
    for (int kw = 0; kw < 4; ++kw)                                          \
      wfrP[slot][kw] = *(const bf16x8*)(w2t + kw * 512 + lane * 8);         \
  }

  bf16x8 wfrP[2][4];
  STAGE_W1(0, rot);
  LOAD_W2(0, rot);

#pragma unroll
  for (int hc0 = 0; hc0 < 8; ++hc0) {
    const int hc = (hc0 + rot) & 7;
    const int cur = hc0 & 1;

    if (hc0 < 7) {
      const int hcn = (hc0 + 1 + rot) & 7;
      STAGE_W1(cur ^ 1, hcn);
      LOAD_W2(cur ^ 1, hcn);
      // retire exactly chunk i's 8 vm-ops; chunk i+1's 8 stay in flight
      asm volatile("s_waitcnt vmcnt(8)" ::: "memory");
    } else {
      asm volatile("s_waitcnt vmcnt(0)" ::: "memory");
    }
    __builtin_amdgcn_sched_barrier(0);
    __builtin_amdgcn_s_barrier();       // wb1[cur] complete block-wide; hs WAR
    __builtin_amdgcn_sched_barrier(0);

    // ---- phase A: S[hid32 x tok32] = W1c-half x x-quarter, K=256
    f32x16 Sp[2];
#pragma unroll
    for (int r = 0; r < 16; ++r) { Sp[0][r] = 0.f; Sp[1][r] = 0.f; }
#pragma unroll
    for (int kw = 0; kw < 16; ++kw) {
      int row = wh * 32 + l31;
      int s = (kw * 2 + hi) ^ (row & 31);
      bf16x8 a = *(const bf16x8*)((const char*)&wb1[cur][0] + row * 512 + s * 16);
      Sp[kw & 1] = MFMA32(a, xB[kw], Sp[kw & 1]);
    }
    f32x16 S = Sp[0] + Sp[1];
    // bias + relu -> hs (8B swizzled writes); bias from LDS (no vmem)
#pragma unroll
    for (int g = 0; g < 4; ++g) {
      int hl = wh * 32 + 8 * g + 4 * hi;   // local hid, 4-aligned
      f32x4 bv = *(const f32x4*)(&b1s[hc * 64 + hl]);
      bf16x4 pk;
#pragma unroll
      for (int r = 0; r < 4; ++r)
        pk[r] = (__bf16)fmaxf(S[4 * g + r] + bv[r], 0.f);
      int m = wtq * 32 + l31;              // token row (0..127)
      int slt = (hl >> 3) ^ (m & 7);
      *(bf16x4*)((char*)hs + m * 128 + slt * 16 + (hl & 7) * 2) = pk;
    }
    asm volatile("s_waitcnt lgkmcnt(0)" ::: "memory");  // hs writes done
    __builtin_amdgcn_sched_barrier(0);
    __builtin_amdgcn_s_barrier();       // hs visible (vmcnt NOT drained)
    __builtin_amdgcn_sched_barrier(0);

    // ---- phase B: acc[out32 x tok128] += W2c^T x h, K=64 (W2 from regs)
#pragma unroll
    for (int kw = 0; kw < 4; ++kw) {
#pragma unroll
      for (int bi = 0; bi < 4; ++bi) {
        int m = bi * 32 + l31;
        int s = (kw * 2 + hi) ^ (m & 7);
        bf16x8 hf = *(const bf16x8*)((const char*)hs + m * 128 + s * 16);
        acc[bi] = MFMA32(wfrP[cur][kw], hf, acc[bi]);
      }
    }
  }
#undef STAGE_W1
#undef LOAD_W2

  // ---- epilogue: pout[srow[t]][oc] = bf16(w * (acc + b2)); 8B stores
#pragma unroll
  for (int bi = 0; bi < 4; ++bi) {
    int tm = bi * 32 + l31;
    if (start + tm < ce) {
      float wv = wgt[tm];
      __bf16* prow = pout + (size_t)srow[tm] * DOUT;
#pragma unroll
      for (int g = 0; g < 4; ++g) {
        int o0 = wid * 32 + 8 * g + 4 * hi;
        f32x4 bv = *(const f32x4*)(&b2s[o0]);
        bf16x4 pk;
#pragma unroll
        for (int r = 0; r < 4; ++r)
          pk[r] = (__bf16)(wv * (acc[bi][4 * g + r] + bv[r]));
        *(bf16x4*)(prow + o0) = pk;
      }
    }
  }
}

// ---------------------------------------------------------------------------
// out[t][c] = pout[0][t][c] + pout[1][t][c]   (streaming, 8 elems/thread)
__global__ __launch_bounds__(256) void combine_kernel(const __bf16* __restrict__ pout,
                                                      float* __restrict__ out) {
  int f = blockIdx.x * 256 + threadIdx.x;  // [0, NTOK*DOUT/8)
  bf16x8 a = *(const bf16x8*)(pout + (size_t)f * 8);
  bf16x8 b = *(const bf16x8*)(pout + (size_t)NTOK * DOUT + (size_t)f * 8);
  float4 o0, o1;
  o0.x = (float)a[0] + (float)b[0];
  o0.y = (float)a[1] + (float)b[1];
  o0.z = (float)a[2] + (float)b[2];
  o0.w = (float)a[3] + (float)b[3];
  o1.x = (float)a[4] + (float)b[4];
  o1.y = (float)a[5] + (float)b[5];
  o1.z = (float)a[6] + (float)b[6];
  o1.w = (float)a[7] + (float)b[7];
  float4* dst = (float4*)(out + (size_t)f * 8);
  dst[0] = o0;
  dst[1] = o1;
}

// ---------------------------------------------------------------------------
extern "C" void kernel_launch(void* const* d_in, const int* in_sizes, int n_in,
                              void* d_out, int out_size, void* d_ws, size_t ws_size,
                              hipStream_t stream) {
  const float* x = (const float*)d_in[0];
  const float* Wg = (const float*)d_in[1];
  const float* W1 = (const float*)d_in[2];
  const float* b1 = (const float*)d_in[3];
  const float* W2 = (const float*)d_in[4];
  const float* b2 = (const float*)d_in[5];
  float* out = (float*)d_out;

  char* ws = (char*)d_ws;
  int* cnt = (int*)(ws + 0);                    //      32 B
  int* btok = (int*)(ws + 256);                 //  512 KiB
  float* bw = (float*)(ws + 524544);            //  512 KiB
  __bf16* xbf = (__bf16*)(ws + 1048832);        //    8 MiB
  __bf16* w1bf = (__bf16*)(ws + 9437440);       //    2 MiB
  __bf16* w2bf = (__bf16*)(ws + 11534592);      //    2 MiB
  __bf16* pout = (__bf16*)(ws + 13631744);      //   16 MiB (end ~29 MiB)

  hipMemsetAsync(cnt, 0, NEXP * sizeof(int), stream);

  prep_kernel<<<dim3(1536), dim3(256), 0, stream>>>(x, Wg, W1, W2, cnt, btok,
                                                    bw, xbf, w1bf, w2bf);
  ffn_kernel<<<dim3(MAXB), dim3(512), 0, stream>>>(xbf, w1bf, w2bf, b1, b2,
                                                   cnt, btok, bw, pout);
  combine_kernel<<<dim3(NTOK * DOUT / 8 / 256), dim3(256), 0, stream>>>(pout, out);
}